// Round 14
// baseline (293.263 us; speedup 1.0000x reference)
//
#include <hip/hip_runtime.h>
#include <hip/hip_fp16.h>

#define EPS 1e-5f
#define ABITS 9           // 512 nodes per target-bucket
#define ACHUNK 4096       // edges per block in bucket pass A
#define BCAP 8192         // padded edge capacity per bucket (avg ~6150, >26 sigma margin)

typedef _Float16 half8 __attribute__((ext_vector_type(8)));
typedef float floatx4 __attribute__((ext_vector_type(4)));

// ---------------- graph prep (2 kernels, padded buckets, no global scan) ----------------
// Normalization factored: gemm scales row r by dinv[r]; agg applies dinv[dst] once.
// csr stores only src indices, in per-bucket padded regions (bucket b at b*BCAP).

// A: per-block LDS histogram -> reserve run per bucket via global fill atomics -> scatter.
__global__ __launch_bounds__(256) void bucketA_kernel(const int* __restrict__ ei, int E,
                                                      int* __restrict__ bucket_fill, int2* __restrict__ tmp) {
    __shared__ int hist[256], lbase[256], lcur[256];
    int t = threadIdx.x;
    hist[t] = 0; lcur[t] = 0;
    __syncthreads();
    int e0 = blockIdx.x * ACHUNK;
    int e1 = e0 + ACHUNK; if (e1 > E) e1 = E;
    for (int e = e0 + t; e < e1; e += 256)
        atomicAdd(&hist[ei[E + e] >> ABITS], 1);
    __syncthreads();
    int h = hist[t];
    if (h) lbase[t] = atomicAdd(&bucket_fill[t], h);
    __syncthreads();
    for (int e = e0 + t; e < e1; e += 256) {
        int r = ei[e], c = ei[E + e];
        int b = c >> ABITS;
        int l = atomicAdd(&lcur[b], 1);
        tmp[(size_t)b * BCAP + lbase[b] + l] = make_int2(r, c);
    }
}

// B: per bucket — stage edges in LDS, count degrees, LDS scan, write rowse(int2)+dinv,
// place src indices into the bucket's padded csr region.
__global__ __launch_bounds__(256) void bucketB_kernel(const int2* __restrict__ tmp,
                                                      const int* __restrict__ bucket_fill,
                                                      int2* __restrict__ rowse, float* __restrict__ dinv,
                                                      int* __restrict__ csr, int n) {
    __shared__ int2 edg[BCAP];    // 64 KB
    __shared__ int cnt[512];
    __shared__ int ps[256];
    __shared__ int lstart[512];
    int b = blockIdx.x, t = threadIdx.x;
    int n0 = b << ABITS;
    int cntN = n - n0; if (cntN > 512) cntN = 512;
    int ne = bucket_fill[b]; if (ne > BCAP) ne = BCAP;
    int base = b * BCAP;
    cnt[t] = 0; cnt[t + 256] = 0;
    for (int idx = t; idx < ne; idx += 256) edg[idx] = tmp[(size_t)base + idx];
    __syncthreads();
    for (int idx = t; idx < ne; idx += 256)
        atomicAdd(&cnt[edg[idx].y - n0], 1);
    __syncthreads();
    int c0 = cnt[2 * t], c1 = cnt[2 * t + 1];
    int s = c0 + c1;
    ps[t] = s;
    __syncthreads();
    for (int off = 1; off < 256; off <<= 1) {
        int u = (t >= off) ? ps[t - off] : 0;
        __syncthreads();
        ps[t] += u;
        __syncthreads();
    }
    int excl = ps[t] - s;
    if (2 * t < cntN) {
        int st = base + excl;
        lstart[2 * t] = st;
        rowse[n0 + 2 * t] = make_int2(st, st + c0);
        dinv[n0 + 2 * t] = rsqrtf((float)(c0 + 1));
    }
    if (2 * t + 1 < cntN) {
        int st = base + excl + c0;
        lstart[2 * t + 1] = st;
        rowse[n0 + 2 * t + 1] = make_int2(st, st + c1);
        dinv[n0 + 2 * t + 1] = rsqrtf((float)(c1 + 1));
    }
    cnt[2 * t] = 0; cnt[2 * t + 1] = 0;   // reuse as cursors
    __syncthreads();
    for (int idx = t; idx < ne; idx += 256) {
        int2 st = edg[idx];
        int lt = st.y - n0;
        int l = atomicAdd(&cnt[lt], 1);
        csr[lstart[lt] + l] = st.x;
    }
}

// ---------------- dense GEMM via MFMA: [n,K] @ [K,64] -> dinv[row] * result (f16) ----------------

template <int K, typename TIN>
__global__ __launch_bounds__(256) void gemm_kernel(const TIN* __restrict__ A, const float* __restrict__ W,
                                                   const float* __restrict__ dinv, __half* __restrict__ out, int n) {
    const int KP = K + 8;
    __shared__ _Float16 Ah[64 * (K + 8)];
    __shared__ _Float16 Wt[64 * (K + 8)];
    int tid = threadIdx.x;

    for (int idx = tid; idx < K * 64; idx += 256) {
        int k = idx >> 6, c = idx & 63;
        Wt[c * KP + k] = (_Float16)W[idx];
    }
    int row0 = blockIdx.x * 64;
    const TIN* Ab = A + (size_t)row0 * K;
    int limit = (n - row0) * K; if (limit > 64 * K) limit = 64 * K;

    if constexpr (sizeof(TIN) == 4) {   // float input
        for (int f = tid * 4; f < 64 * K; f += 1024) {
            float4 v = make_float4(0.f, 0.f, 0.f, 0.f);
            if (f + 3 < limit) {
                v = *(const float4*)((const float*)Ab + f);
            } else {
                if (f + 0 < limit) v.x = ((const float*)Ab)[f + 0];
                if (f + 1 < limit) v.y = ((const float*)Ab)[f + 1];
                if (f + 2 < limit) v.z = ((const float*)Ab)[f + 2];
            }
            int row = f / K, k = f % K;
            _Float16* dst = Ah + row * KP + k;
            dst[0] = (_Float16)v.x; dst[1] = (_Float16)v.y;
            dst[2] = (_Float16)v.z; dst[3] = (_Float16)v.w;
        }
    } else {                            // fp16 input: straight copy
        for (int f = tid * 8; f < 64 * K; f += 2048) {
            uint4 v = make_uint4(0, 0, 0, 0);
            if (f + 7 < limit) {
                v = *(const uint4*)((const __half*)Ab + f);
            } else {
                const __half* hp = (const __half*)Ab;
                __half tmp8[8];
                for (int j = 0; j < 8; ++j) tmp8[j] = (f + j < limit) ? hp[f + j] : __half(0);
                v = *(const uint4*)tmp8;
            }
            int row = f / K, k = f % K;
            *(uint4*)(Ah + row * KP + k) = v;
        }
    }
    __syncthreads();

    int w = tid >> 6, lane = tid & 63;
    int m = lane & 15, quad = lane >> 4;
    const _Float16* Aw = Ah + (size_t)(w * 16 + m) * KP + quad * 8;
    const _Float16* Bw = Wt + (size_t)m * KP + quad * 8;

    floatx4 acc0 = {0.f, 0.f, 0.f, 0.f}, acc1 = acc0, acc2 = acc0, acc3 = acc0;
    for (int k0 = 0; k0 < K; k0 += 32) {
        half8 a  = *(const half8*)(Aw + k0);
        half8 b0 = *(const half8*)(Bw + 0 * 16 * KP + k0);
        half8 b1 = *(const half8*)(Bw + 1 * 16 * KP + k0);
        half8 b2 = *(const half8*)(Bw + 2 * 16 * KP + k0);
        half8 b3 = *(const half8*)(Bw + 3 * 16 * KP + k0);
        acc0 = __builtin_amdgcn_mfma_f32_16x16x32_f16(a, b0, acc0, 0, 0, 0);
        acc1 = __builtin_amdgcn_mfma_f32_16x16x32_f16(a, b1, acc1, 0, 0, 0);
        acc2 = __builtin_amdgcn_mfma_f32_16x16x32_f16(a, b2, acc2, 0, 0, 0);
        acc3 = __builtin_amdgcn_mfma_f32_16x16x32_f16(a, b3, acc3, 0, 0, 0);
    }

    int rbase = row0 + w * 16 + quad * 4;
#pragma unroll
    for (int r = 0; r < 4; ++r) {
        int row = rbase + r;
        if (row < n) {
            float dv = dinv[row];
            __half* o = out + (size_t)row * 64 + m;
            o[0]  = __float2half(acc0[r] * dv);
            o[16] = __float2half(acc1[r] * dv);
            o[32] = __float2half(acc2[r] * dv);
            o[48] = __float2half(acc3[r] * dv);
        }
    }
}

// ---------------- aggregation kernels ----------------
// agg_half: FEATURE-SPLIT. Grid = 2 phases: blocks [0,nbH) do features 0..31,
// [nbH,2nbH) do 32..63. Working set per phase = 6.4 MB (vs 12.8) -> higher L2
// hit rate; each edge gather is ONE 64 B line. Wave = 8 groups x 8 lanes, one
// node per group, lane owns 4 features (8 B). Unroll-8 -> 64 lines in flight/wave.

__device__ __forceinline__ void agg_add4(float4& a, uint2 raw) {
    float2 p0 = __half22float2(*(const __half2*)&raw.x);
    float2 p1 = __half22float2(*(const __half2*)&raw.y);
    a.x += p0.x; a.y += p0.y; a.z += p1.x; a.w += p1.y;
}

__global__ __launch_bounds__(256) void agg_half_kernel(const __half* __restrict__ t, const float* __restrict__ dinv,
                                                       const int2* __restrict__ rowse, const int* __restrict__ csr,
                                                       const float* __restrict__ bias, const float* __restrict__ gamma,
                                                       const float* __restrict__ beta, const float* __restrict__ mean,
                                                       const float* __restrict__ var, __half* __restrict__ hout,
                                                       int n) {
    int nbH = gridDim.x >> 1;
    int hb = (blockIdx.x >= nbH) ? 1 : 0;
    int bx = hb ? (blockIdx.x - nbH) : blockIdx.x;
    int wave = threadIdx.x >> 6;
    int lane = threadIdx.x & 63;
    int g = lane >> 3;          // group = node slot
    int fl = lane & 7;          // lane owns features hb*32 + fl*4 .. +3
    int i = (bx * 4 + wave) * 8 + g;
    if (i >= n) return;

    const __half* tb = t + hb * 32 + fl * 4;
    float4 acc = make_float4(0.f, 0.f, 0.f, 0.f);

    uint2 self = *(const uint2*)(tb + (size_t)i * 64);
    agg_add4(acc, self);

    int2 se = rowse[i];
    int e = se.x, e1 = se.y;
    for (; e + 8 <= e1; e += 8) {
        int s0 = csr[e + 0], s1 = csr[e + 1], s2 = csr[e + 2], s3 = csr[e + 3];
        int s4 = csr[e + 4], s5 = csr[e + 5], s6 = csr[e + 6], s7 = csr[e + 7];
        uint2 r0 = *(const uint2*)(tb + (size_t)s0 * 64);
        uint2 r1 = *(const uint2*)(tb + (size_t)s1 * 64);
        uint2 r2 = *(const uint2*)(tb + (size_t)s2 * 64);
        uint2 r3 = *(const uint2*)(tb + (size_t)s3 * 64);
        uint2 r4 = *(const uint2*)(tb + (size_t)s4 * 64);
        uint2 r5 = *(const uint2*)(tb + (size_t)s5 * 64);
        uint2 r6 = *(const uint2*)(tb + (size_t)s6 * 64);
        uint2 r7 = *(const uint2*)(tb + (size_t)s7 * 64);
        agg_add4(acc, r0); agg_add4(acc, r1); agg_add4(acc, r2); agg_add4(acc, r3);
        agg_add4(acc, r4); agg_add4(acc, r5); agg_add4(acc, r6); agg_add4(acc, r7);
    }
    if (e + 4 <= e1) {
        int s0 = csr[e + 0], s1 = csr[e + 1], s2 = csr[e + 2], s3 = csr[e + 3];
        uint2 r0 = *(const uint2*)(tb + (size_t)s0 * 64);
        uint2 r1 = *(const uint2*)(tb + (size_t)s1 * 64);
        uint2 r2 = *(const uint2*)(tb + (size_t)s2 * 64);
        uint2 r3 = *(const uint2*)(tb + (size_t)s3 * 64);
        agg_add4(acc, r0); agg_add4(acc, r1); agg_add4(acc, r2); agg_add4(acc, r3);
        e += 4;
    }
    if (e + 2 <= e1) {
        int s0 = csr[e + 0], s1 = csr[e + 1];
        uint2 r0 = *(const uint2*)(tb + (size_t)s0 * 64);
        uint2 r1 = *(const uint2*)(tb + (size_t)s1 * 64);
        agg_add4(acc, r0); agg_add4(acc, r1);
        e += 2;
    }
    if (e < e1) {
        uint2 r0 = *(const uint2*)(tb + (size_t)csr[e] * 64);
        agg_add4(acc, r0);
    }

    float di = dinv[i];
    acc.x *= di; acc.y *= di; acc.z *= di; acc.w *= di;

    int f4 = hb * 8 + fl;
    float4 bb = ((const float4*)bias)[f4];
    float4 gg = ((const float4*)gamma)[f4];
    float4 be = ((const float4*)beta)[f4];
    float4 mm = ((const float4*)mean)[f4];
    float4 vv = ((const float4*)var)[f4];
    float4 res;
    res.x = fmaxf((acc.x + bb.x - mm.x) * (gg.x * rsqrtf(vv.x + EPS)) + be.x, 0.f);
    res.y = fmaxf((acc.y + bb.y - mm.y) * (gg.y * rsqrtf(vv.y + EPS)) + be.y, 0.f);
    res.z = fmaxf((acc.z + bb.z - mm.z) * (gg.z * rsqrtf(vv.z + EPS)) + be.z, 0.f);
    res.w = fmaxf((acc.w + bb.w - mm.w) * (gg.w * rsqrtf(vv.w + EPS)) + be.w, 0.f);

    __half2 h0 = __floats2half2_rn(res.x, res.y);
    __half2 h1 = __floats2half2_rn(res.z, res.w);
    uint2 pk;
    pk.x = *(unsigned*)&h0; pk.y = *(unsigned*)&h1;
    ((uint2*)hout)[(size_t)i * 16 + f4] = pk;
}

// agg_full: full-row (layer 2), fused classifier. Wave = 8 groups x 8 lanes,
// lane owns a feature octet (16 B).

__device__ __forceinline__ void agg_add8(float4& lo, float4& hi, uint4 raw) {
    float2 p0 = __half22float2(*(const __half2*)&raw.x);
    float2 p1 = __half22float2(*(const __half2*)&raw.y);
    float2 p2 = __half22float2(*(const __half2*)&raw.z);
    float2 p3 = __half22float2(*(const __half2*)&raw.w);
    lo.x += p0.x; lo.y += p0.y; lo.z += p1.x; lo.w += p1.y;
    hi.x += p2.x; hi.y += p2.y; hi.z += p3.x; hi.w += p3.y;
}

__global__ __launch_bounds__(256) void agg_cls_kernel(const __half* __restrict__ t, const float* __restrict__ dinv,
                                                      const int2* __restrict__ rowse, const int* __restrict__ csr,
                                                      const float* __restrict__ bias, const float* __restrict__ gamma,
                                                      const float* __restrict__ beta, const float* __restrict__ mean,
                                                      const float* __restrict__ var, float* __restrict__ fout,
                                                      const float* __restrict__ cls_w, const float* __restrict__ cls_b,
                                                      int n) {
    int wave = threadIdx.x >> 6;
    int lane = threadIdx.x & 63;
    int g = lane >> 3;
    int fl = lane & 7;
    int i = (blockIdx.x * (blockDim.x >> 6) + wave) * 8 + g;
    if (i >= n) return;

    float4 lo = make_float4(0.f, 0.f, 0.f, 0.f);
    float4 hi = make_float4(0.f, 0.f, 0.f, 0.f);

    uint4 self = *(const uint4*)(t + (size_t)i * 64 + fl * 8);
    agg_add8(lo, hi, self);

    int2 se = rowse[i];
    int e = se.x, e1 = se.y;
    for (; e + 8 <= e1; e += 8) {
        int s0 = csr[e + 0], s1 = csr[e + 1], s2 = csr[e + 2], s3 = csr[e + 3];
        int s4 = csr[e + 4], s5 = csr[e + 5], s6 = csr[e + 6], s7 = csr[e + 7];
        uint4 r0 = *(const uint4*)(t + (size_t)s0 * 64 + fl * 8);
        uint4 r1 = *(const uint4*)(t + (size_t)s1 * 64 + fl * 8);
        uint4 r2 = *(const uint4*)(t + (size_t)s2 * 64 + fl * 8);
        uint4 r3 = *(const uint4*)(t + (size_t)s3 * 64 + fl * 8);
        uint4 r4 = *(const uint4*)(t + (size_t)s4 * 64 + fl * 8);
        uint4 r5 = *(const uint4*)(t + (size_t)s5 * 64 + fl * 8);
        uint4 r6 = *(const uint4*)(t + (size_t)s6 * 64 + fl * 8);
        uint4 r7 = *(const uint4*)(t + (size_t)s7 * 64 + fl * 8);
        agg_add8(lo, hi, r0); agg_add8(lo, hi, r1); agg_add8(lo, hi, r2); agg_add8(lo, hi, r3);
        agg_add8(lo, hi, r4); agg_add8(lo, hi, r5); agg_add8(lo, hi, r6); agg_add8(lo, hi, r7);
    }
    if (e + 4 <= e1) {
        int s0 = csr[e + 0], s1 = csr[e + 1], s2 = csr[e + 2], s3 = csr[e + 3];
        uint4 r0 = *(const uint4*)(t + (size_t)s0 * 64 + fl * 8);
        uint4 r1 = *(const uint4*)(t + (size_t)s1 * 64 + fl * 8);
        uint4 r2 = *(const uint4*)(t + (size_t)s2 * 64 + fl * 8);
        uint4 r3 = *(const uint4*)(t + (size_t)s3 * 64 + fl * 8);
        agg_add8(lo, hi, r0); agg_add8(lo, hi, r1); agg_add8(lo, hi, r2); agg_add8(lo, hi, r3);
        e += 4;
    }
    if (e + 2 <= e1) {
        int s0 = csr[e + 0], s1 = csr[e + 1];
        uint4 r0 = *(const uint4*)(t + (size_t)s0 * 64 + fl * 8);
        uint4 r1 = *(const uint4*)(t + (size_t)s1 * 64 + fl * 8);
        agg_add8(lo, hi, r0); agg_add8(lo, hi, r1);
        e += 2;
    }
    if (e < e1) {
        uint4 r0 = *(const uint4*)(t + (size_t)csr[e] * 64 + fl * 8);
        agg_add8(lo, hi, r0);
    }

    float di = dinv[i];
    lo.x *= di; lo.y *= di; lo.z *= di; lo.w *= di;
    hi.x *= di; hi.y *= di; hi.z *= di; hi.w *= di;

    float4 bbL = ((const float4*)bias)[2 * fl],  bbH = ((const float4*)bias)[2 * fl + 1];
    float4 ggL = ((const float4*)gamma)[2 * fl], ggH = ((const float4*)gamma)[2 * fl + 1];
    float4 beL = ((const float4*)beta)[2 * fl],  beH = ((const float4*)beta)[2 * fl + 1];
    float4 mmL = ((const float4*)mean)[2 * fl],  mmH = ((const float4*)mean)[2 * fl + 1];
    float4 vvL = ((const float4*)var)[2 * fl],   vvH = ((const float4*)var)[2 * fl + 1];
    float4 resL, resH;
    resL.x = fmaxf((lo.x + bbL.x - mmL.x) * (ggL.x * rsqrtf(vvL.x + EPS)) + beL.x, 0.f);
    resL.y = fmaxf((lo.y + bbL.y - mmL.y) * (ggL.y * rsqrtf(vvL.y + EPS)) + beL.y, 0.f);
    resL.z = fmaxf((lo.z + bbL.z - mmL.z) * (ggL.z * rsqrtf(vvL.z + EPS)) + beL.z, 0.f);
    resL.w = fmaxf((lo.w + bbL.w - mmL.w) * (ggL.w * rsqrtf(vvL.w + EPS)) + beL.w, 0.f);
    resH.x = fmaxf((hi.x + bbH.x - mmH.x) * (ggH.x * rsqrtf(vvH.x + EPS)) + beH.x, 0.f);
    resH.y = fmaxf((hi.y + bbH.y - mmH.y) * (ggH.y * rsqrtf(vvH.y + EPS)) + beH.y, 0.f);
    resH.z = fmaxf((hi.z + bbH.z - mmH.z) * (ggH.z * rsqrtf(vvH.z + EPS)) + beH.z, 0.f);
    resH.w = fmaxf((hi.w + bbH.w - mmH.w) * (ggH.w * rsqrtf(vvH.w + EPS)) + beH.w, 0.f);

    const float4* cw = (const float4*)cls_w;
    float4 cwA = cw[4 * fl + 0], cwB = cw[4 * fl + 1], cwC = cw[4 * fl + 2], cwD = cw[4 * fl + 3];
    float c0 = resL.x * cwA.x + resL.y * cwA.z + resL.z * cwB.x + resL.w * cwB.z
             + resH.x * cwC.x + resH.y * cwC.z + resH.z * cwD.x + resH.w * cwD.z;
    float c1 = resL.x * cwA.y + resL.y * cwA.w + resL.z * cwB.y + resL.w * cwB.w
             + resH.x * cwC.y + resH.y * cwC.w + resH.z * cwD.y + resH.w * cwD.w;
    for (int off = 4; off > 0; off >>= 1) {
        c0 += __shfl_xor(c0, off);
        c1 += __shfl_xor(c1, off);
    }
    if (fl == 0) {
        fout[(size_t)i * 2 + 0] = c0 + cls_b[0];
        fout[(size_t)i * 2 + 1] = c1 + cls_b[1];
    }
}

// ---------------- launch ----------------

extern "C" void kernel_launch(void* const* d_in, const int* in_sizes, int n_in,
                              void* d_out, int out_size, void* d_ws, size_t ws_size,
                              hipStream_t stream) {
    const float* x      = (const float*)d_in[0];
    const int*   ei     = (const int*)d_in[1];
    const float* w0     = (const float*)d_in[2];
    const float* w1     = (const float*)d_in[3];
    const float* w2     = (const float*)d_in[4];
    const float* biases = (const float*)d_in[5];
    const float* gamma  = (const float*)d_in[6];
    const float* beta   = (const float*)d_in[7];
    const float* rmean  = (const float*)d_in[8];
    const float* rvar   = (const float*)d_in[9];
    const float* cls_w  = (const float*)d_in[10];
    const float* cls_b  = (const float*)d_in[11];
    float* out = (float*)d_out;

    const int IN = 128, H = 64;
    const int N = in_sizes[0] / IN;   // 100000
    const int E = in_sizes[1] / 2;    // 1200000

    char* p = (char*)d_ws;
    auto carve = [&](size_t bytes) { void* q = (void*)p; p += (bytes + 255) & ~(size_t)255; return q; };
    float* dinv    = (float*)carve((size_t)N * 4);
    int2*  rowse   = (int2*)carve((size_t)N * 8);
    int*   bucket_fill = (int*)carve((size_t)256 * 4);
    int2*  tmp     = (int2*)carve((size_t)256 * BCAP * 8);
    int*   csr     = (int*)carve((size_t)256 * BCAP * 4);
    __half* tbuf   = (__half*)carve((size_t)N * H * 2);
    __half* hbuf   = (__half*)carve((size_t)N * H * 2);

    int nbuckets = (N + (1 << ABITS) - 1) >> ABITS;   // 196 for N=100000
    int na = (E + ACHUNK - 1) / ACHUNK;               // 293

    hipMemsetAsync(bucket_fill, 0, (size_t)256 * 4, stream);
    bucketA_kernel<<<na, 256, 0, stream>>>(ei, E, bucket_fill, tmp);
    bucketB_kernel<<<nbuckets, 256, 0, stream>>>(tmp, bucket_fill, rowse, dinv, csr, N);

    int gemm_grid = (N + 63) / 64;
    int nbH = (N + 31) / 32;         // 32 nodes per block
    int agg_half_grid = 2 * nbH;     // phase 0: features 0-31, phase 1: 32-63
    int agg_cls_grid  = nbH;

    // layer 0
    gemm_kernel<128, float><<<gemm_grid, 256, 0, stream>>>(x, w0, dinv, tbuf, N);
    agg_half_kernel<<<agg_half_grid, 256, 0, stream>>>(tbuf, dinv, rowse, csr,
        biases + 0, gamma + 0, beta + 0, rmean + 0, rvar + 0, hbuf, N);
    // layer 1
    gemm_kernel<64, __half><<<gemm_grid, 256, 0, stream>>>(hbuf, w1, dinv, tbuf, N);
    agg_half_kernel<<<agg_half_grid, 256, 0, stream>>>(tbuf, dinv, rowse, csr,
        biases + H, gamma + H, beta + H, rmean + H, rvar + H, hbuf, N);
    // layer 2 + classifier (full row)
    gemm_kernel<64, __half><<<gemm_grid, 256, 0, stream>>>(hbuf, w2, dinv, tbuf, N);
    agg_cls_kernel<<<agg_cls_grid, 256, 0, stream>>>(tbuf, dinv, rowse, csr,
        biases + 2 * H, gamma + 2 * H, beta + 2 * H, rmean + 2 * H, rvar + 2 * H, out, cls_w, cls_b, N);
}

// Round 15
// 263.390 us; speedup vs baseline: 1.1134x; 1.1134x over previous
//
#include <hip/hip_runtime.h>
#include <hip/hip_fp16.h>

#define EPS 1e-5f
#define ABITS 9           // 512 nodes per target-bucket
#define ACHUNK 4096       // edges per block in bucket pass A
#define BCAP 8192         // padded edge capacity per bucket (avg ~6150, >26 sigma margin)
#define CSHIFT 14         // src-chunk = src >> 14 (2.1 MB of t per chunk)
#define NCHUNK 8

typedef _Float16 half8 __attribute__((ext_vector_type(8)));
typedef float floatx4 __attribute__((ext_vector_type(4)));

// ---------------- graph prep (2 kernels, padded buckets, no global scan) ----------------
// Normalization factored: gemm scales row r by dinv[r]; agg applies dinv[dst] once.
// csr stores only src indices. Each node's list is ordered by src-chunk so that
// concurrently-running waves sweep t[] in ~2 MB bands that stay L2-resident.

// A: per-block LDS histogram -> reserve run per bucket via global fill atomics -> scatter.
__global__ __launch_bounds__(256) void bucketA_kernel(const int* __restrict__ ei, int E,
                                                      int* __restrict__ bucket_fill, int2* __restrict__ tmp) {
    __shared__ int hist[256], lbase[256], lcur[256];
    int t = threadIdx.x;
    hist[t] = 0; lcur[t] = 0;
    __syncthreads();
    int e0 = blockIdx.x * ACHUNK;
    int e1 = e0 + ACHUNK; if (e1 > E) e1 = E;
    for (int e = e0 + t; e < e1; e += 256)
        atomicAdd(&hist[ei[E + e] >> ABITS], 1);
    __syncthreads();
    int h = hist[t];
    if (h) lbase[t] = atomicAdd(&bucket_fill[t], h);
    __syncthreads();
    for (int e = e0 + t; e < e1; e += 256) {
        int r = ei[e], c = ei[E + e];
        int b = c >> ABITS;
        int l = atomicAdd(&lcur[b], 1);
        tmp[(size_t)b * BCAP + lbase[b] + l] = make_int2(r, c);
    }
}

// B: per bucket — stage edges in LDS, count (dst,chunk), scan, write rowse(int2)+dinv,
// place src indices grouped by src-chunk within each node's list.
__global__ __launch_bounds__(256) void bucketB_kernel(const int2* __restrict__ tmp,
                                                      const int* __restrict__ bucket_fill,
                                                      int2* __restrict__ rowse, float* __restrict__ dinv,
                                                      int* __restrict__ csr, int n) {
    __shared__ int2 edg[BCAP];              // 64 KB
    __shared__ int cnt2[512 * NCHUNK];      // 16 KB: counts -> seg starts -> cursors
    __shared__ int ps[256];
    int b = blockIdx.x, t = threadIdx.x;
    int n0 = b << ABITS;
    int cntN = n - n0; if (cntN > 512) cntN = 512;
    int ne = bucket_fill[b]; if (ne > BCAP) ne = BCAP;
    int base = b * BCAP;
    for (int i = t; i < 512 * NCHUNK; i += 256) cnt2[i] = 0;
    for (int idx = t; idx < ne; idx += 256) edg[idx] = tmp[(size_t)base + idx];
    __syncthreads();
    for (int idx = t; idx < ne; idx += 256) {
        int2 e = edg[idx];
        atomicAdd(&cnt2[(e.y - n0) * NCHUNK + (e.x >> CSHIFT)], 1);
    }
    __syncthreads();
    // per-node totals (2 nodes per thread)
    int c0 = 0, c1 = 0;
#pragma unroll
    for (int c = 0; c < NCHUNK; ++c) {
        c0 += cnt2[(2 * t) * NCHUNK + c];
        c1 += cnt2[(2 * t + 1) * NCHUNK + c];
    }
    int s = c0 + c1;
    ps[t] = s;
    __syncthreads();
    for (int off = 1; off < 256; off <<= 1) {
        int u = (t >= off) ? ps[t - off] : 0;
        __syncthreads();
        ps[t] += u;
        __syncthreads();
    }
    int excl = ps[t] - s;
    int st0 = base + excl, st1 = base + excl + c0;
    if (2 * t < cntN) {
        rowse[n0 + 2 * t] = make_int2(st0, st0 + c0);
        dinv[n0 + 2 * t] = rsqrtf((float)(c0 + 1));
    }
    if (2 * t + 1 < cntN) {
        rowse[n0 + 2 * t + 1] = make_int2(st1, st1 + c1);
        dinv[n0 + 2 * t + 1] = rsqrtf((float)(c1 + 1));
    }
    // convert cnt2 counts -> segment start cursors (in place, per node sequential)
    int run = st0;
#pragma unroll
    for (int c = 0; c < NCHUNK; ++c) {
        int v = cnt2[(2 * t) * NCHUNK + c];
        cnt2[(2 * t) * NCHUNK + c] = run;
        run += v;
    }
    run = st1;
#pragma unroll
    for (int c = 0; c < NCHUNK; ++c) {
        int v = cnt2[(2 * t + 1) * NCHUNK + c];
        cnt2[(2 * t + 1) * NCHUNK + c] = run;
        run += v;
    }
    __syncthreads();
    for (int idx = t; idx < ne; idx += 256) {
        int2 e = edg[idx];
        int key = (e.y - n0) * NCHUNK + (e.x >> CSHIFT);
        int pos = atomicAdd(&cnt2[key], 1);
        csr[pos] = e.x;
    }
}

// ---------------- dense GEMM via MFMA: [n,K] @ [K,64] -> dinv[row] * result (f16) ----------------

template <int K, typename TIN>
__global__ __launch_bounds__(256) void gemm_kernel(const TIN* __restrict__ A, const float* __restrict__ W,
                                                   const float* __restrict__ dinv, __half* __restrict__ out, int n) {
    const int KP = K + 8;
    __shared__ _Float16 Ah[64 * (K + 8)];
    __shared__ _Float16 Wt[64 * (K + 8)];
    int tid = threadIdx.x;

    for (int idx = tid; idx < K * 64; idx += 256) {
        int k = idx >> 6, c = idx & 63;
        Wt[c * KP + k] = (_Float16)W[idx];
    }
    int row0 = blockIdx.x * 64;
    const TIN* Ab = A + (size_t)row0 * K;
    int limit = (n - row0) * K; if (limit > 64 * K) limit = 64 * K;

    if constexpr (sizeof(TIN) == 4) {   // float input
        for (int f = tid * 4; f < 64 * K; f += 1024) {
            float4 v = make_float4(0.f, 0.f, 0.f, 0.f);
            if (f + 3 < limit) {
                v = *(const float4*)((const float*)Ab + f);
            } else {
                if (f + 0 < limit) v.x = ((const float*)Ab)[f + 0];
                if (f + 1 < limit) v.y = ((const float*)Ab)[f + 1];
                if (f + 2 < limit) v.z = ((const float*)Ab)[f + 2];
            }
            int row = f / K, k = f % K;
            _Float16* dst = Ah + row * KP + k;
            dst[0] = (_Float16)v.x; dst[1] = (_Float16)v.y;
            dst[2] = (_Float16)v.z; dst[3] = (_Float16)v.w;
        }
    } else {                            // fp16 input: straight copy
        for (int f = tid * 8; f < 64 * K; f += 2048) {
            uint4 v = make_uint4(0, 0, 0, 0);
            if (f + 7 < limit) {
                v = *(const uint4*)((const __half*)Ab + f);
            } else {
                const __half* hp = (const __half*)Ab;
                __half tmp8[8];
                for (int j = 0; j < 8; ++j) tmp8[j] = (f + j < limit) ? hp[f + j] : __half(0);
                v = *(const uint4*)tmp8;
            }
            int row = f / K, k = f % K;
            *(uint4*)(Ah + row * KP + k) = v;
        }
    }
    __syncthreads();

    int w = tid >> 6, lane = tid & 63;
    int m = lane & 15, quad = lane >> 4;
    const _Float16* Aw = Ah + (size_t)(w * 16 + m) * KP + quad * 8;
    const _Float16* Bw = Wt + (size_t)m * KP + quad * 8;

    floatx4 acc0 = {0.f, 0.f, 0.f, 0.f}, acc1 = acc0, acc2 = acc0, acc3 = acc0;
    for (int k0 = 0; k0 < K; k0 += 32) {
        half8 a  = *(const half8*)(Aw + k0);
        half8 b0 = *(const half8*)(Bw + 0 * 16 * KP + k0);
        half8 b1 = *(const half8*)(Bw + 1 * 16 * KP + k0);
        half8 b2 = *(const half8*)(Bw + 2 * 16 * KP + k0);
        half8 b3 = *(const half8*)(Bw + 3 * 16 * KP + k0);
        acc0 = __builtin_amdgcn_mfma_f32_16x16x32_f16(a, b0, acc0, 0, 0, 0);
        acc1 = __builtin_amdgcn_mfma_f32_16x16x32_f16(a, b1, acc1, 0, 0, 0);
        acc2 = __builtin_amdgcn_mfma_f32_16x16x32_f16(a, b2, acc2, 0, 0, 0);
        acc3 = __builtin_amdgcn_mfma_f32_16x16x32_f16(a, b3, acc3, 0, 0, 0);
    }

    int rbase = row0 + w * 16 + quad * 4;
#pragma unroll
    for (int r = 0; r < 4; ++r) {
        int row = rbase + r;
        if (row < n) {
            float dv = dinv[row];
            __half* o = out + (size_t)row * 64 + m;
            o[0]  = __float2half(acc0[r] * dv);
            o[16] = __float2half(acc1[r] * dv);
            o[32] = __float2half(acc2[r] * dv);
            o[48] = __float2half(acc3[r] * dv);
        }
    }
}

// ---------------- aggregation + bias + BN(eval) + ReLU (+classifier) ----------------
// Full-row gather (8 lanes x 16 B = one 128 B line per edge — matches TCC fetch
// granularity; R14's feature-split DOUBLED fetch). Wave = 8 independent 8-lane
// groups, one node per group. Unroll 8/4/2/1 -> up to 64 lines in flight/wave.

__device__ __forceinline__ void agg_add8(float4& lo, float4& hi, uint4 raw) {
    float2 p0 = __half22float2(*(const __half2*)&raw.x);
    float2 p1 = __half22float2(*(const __half2*)&raw.y);
    float2 p2 = __half22float2(*(const __half2*)&raw.z);
    float2 p3 = __half22float2(*(const __half2*)&raw.w);
    lo.x += p0.x; lo.y += p0.y; lo.z += p1.x; lo.w += p1.y;
    hi.x += p2.x; hi.y += p2.y; hi.z += p3.x; hi.w += p3.y;
}

template <bool FUSE_CLS>
__global__ __launch_bounds__(256) void agg_kernel(const __half* __restrict__ t, const float* __restrict__ dinv,
                                                  const int2* __restrict__ rowse, const int* __restrict__ csr,
                                                  const float* __restrict__ bias, const float* __restrict__ gamma,
                                                  const float* __restrict__ beta, const float* __restrict__ mean,
                                                  const float* __restrict__ var, __half* __restrict__ hout,
                                                  float* __restrict__ fout,
                                                  const float* __restrict__ cls_w, const float* __restrict__ cls_b,
                                                  int n) {
    int wave = threadIdx.x >> 6;
    int lane = threadIdx.x & 63;
    int g = lane >> 3;          // group 0..7 = node slot
    int fl = lane & 7;          // feature octet: features 8fl..8fl+7
    int i = (blockIdx.x * (blockDim.x >> 6) + wave) * 8 + g;
    if (i >= n) return;

    float4 lo = make_float4(0.f, 0.f, 0.f, 0.f);
    float4 hi = make_float4(0.f, 0.f, 0.f, 0.f);

    uint4 self = *(const uint4*)(t + (size_t)i * 64 + fl * 8);
    agg_add8(lo, hi, self);

    int2 se = rowse[i];
    int e = se.x, e1 = se.y;
    for (; e + 8 <= e1; e += 8) {
        int s0 = csr[e + 0], s1 = csr[e + 1], s2 = csr[e + 2], s3 = csr[e + 3];
        int s4 = csr[e + 4], s5 = csr[e + 5], s6 = csr[e + 6], s7 = csr[e + 7];
        uint4 r0 = *(const uint4*)(t + (size_t)s0 * 64 + fl * 8);
        uint4 r1 = *(const uint4*)(t + (size_t)s1 * 64 + fl * 8);
        uint4 r2 = *(const uint4*)(t + (size_t)s2 * 64 + fl * 8);
        uint4 r3 = *(const uint4*)(t + (size_t)s3 * 64 + fl * 8);
        uint4 r4 = *(const uint4*)(t + (size_t)s4 * 64 + fl * 8);
        uint4 r5 = *(const uint4*)(t + (size_t)s5 * 64 + fl * 8);
        uint4 r6 = *(const uint4*)(t + (size_t)s6 * 64 + fl * 8);
        uint4 r7 = *(const uint4*)(t + (size_t)s7 * 64 + fl * 8);
        agg_add8(lo, hi, r0); agg_add8(lo, hi, r1); agg_add8(lo, hi, r2); agg_add8(lo, hi, r3);
        agg_add8(lo, hi, r4); agg_add8(lo, hi, r5); agg_add8(lo, hi, r6); agg_add8(lo, hi, r7);
    }
    if (e + 4 <= e1) {
        int s0 = csr[e + 0], s1 = csr[e + 1], s2 = csr[e + 2], s3 = csr[e + 3];
        uint4 r0 = *(const uint4*)(t + (size_t)s0 * 64 + fl * 8);
        uint4 r1 = *(const uint4*)(t + (size_t)s1 * 64 + fl * 8);
        uint4 r2 = *(const uint4*)(t + (size_t)s2 * 64 + fl * 8);
        uint4 r3 = *(const uint4*)(t + (size_t)s3 * 64 + fl * 8);
        agg_add8(lo, hi, r0); agg_add8(lo, hi, r1); agg_add8(lo, hi, r2); agg_add8(lo, hi, r3);
        e += 4;
    }
    if (e + 2 <= e1) {
        int s0 = csr[e + 0], s1 = csr[e + 1];
        uint4 r0 = *(const uint4*)(t + (size_t)s0 * 64 + fl * 8);
        uint4 r1 = *(const uint4*)(t + (size_t)s1 * 64 + fl * 8);
        agg_add8(lo, hi, r0); agg_add8(lo, hi, r1);
        e += 2;
    }
    if (e < e1) {
        uint4 r0 = *(const uint4*)(t + (size_t)csr[e] * 64 + fl * 8);
        agg_add8(lo, hi, r0);
    }

    float di = dinv[i];
    lo.x *= di; lo.y *= di; lo.z *= di; lo.w *= di;
    hi.x *= di; hi.y *= di; hi.z *= di; hi.w *= di;

    float4 bbL = ((const float4*)bias)[2 * fl],  bbH = ((const float4*)bias)[2 * fl + 1];
    float4 ggL = ((const float4*)gamma)[2 * fl], ggH = ((const float4*)gamma)[2 * fl + 1];
    float4 beL = ((const float4*)beta)[2 * fl],  beH = ((const float4*)beta)[2 * fl + 1];
    float4 mmL = ((const float4*)mean)[2 * fl],  mmH = ((const float4*)mean)[2 * fl + 1];
    float4 vvL = ((const float4*)var)[2 * fl],   vvH = ((const float4*)var)[2 * fl + 1];
    float4 resL, resH;
    resL.x = fmaxf((lo.x + bbL.x - mmL.x) * (ggL.x * rsqrtf(vvL.x + EPS)) + beL.x, 0.f);
    resL.y = fmaxf((lo.y + bbL.y - mmL.y) * (ggL.y * rsqrtf(vvL.y + EPS)) + beL.y, 0.f);
    resL.z = fmaxf((lo.z + bbL.z - mmL.z) * (ggL.z * rsqrtf(vvL.z + EPS)) + beL.z, 0.f);
    resL.w = fmaxf((lo.w + bbL.w - mmL.w) * (ggL.w * rsqrtf(vvL.w + EPS)) + beL.w, 0.f);
    resH.x = fmaxf((hi.x + bbH.x - mmH.x) * (ggH.x * rsqrtf(vvH.x + EPS)) + beH.x, 0.f);
    resH.y = fmaxf((hi.y + bbH.y - mmH.y) * (ggH.y * rsqrtf(vvH.y + EPS)) + beH.y, 0.f);
    resH.z = fmaxf((hi.z + bbH.z - mmH.z) * (ggH.z * rsqrtf(vvH.z + EPS)) + beH.z, 0.f);
    resH.w = fmaxf((hi.w + bbH.w - mmH.w) * (ggH.w * rsqrtf(vvH.w + EPS)) + beH.w, 0.f);

    if (!FUSE_CLS) {
        __half2 h0 = __floats2half2_rn(resL.x, resL.y);
        __half2 h1 = __floats2half2_rn(resL.z, resL.w);
        __half2 h2 = __floats2half2_rn(resH.x, resH.y);
        __half2 h3 = __floats2half2_rn(resH.z, resH.w);
        uint4 pk;
        pk.x = *(unsigned*)&h0; pk.y = *(unsigned*)&h1;
        pk.z = *(unsigned*)&h2; pk.w = *(unsigned*)&h3;
        ((uint4*)hout)[(size_t)i * 8 + fl] = pk;
    } else {
        const float4* cw = (const float4*)cls_w;
        float4 cwA = cw[4 * fl + 0], cwB = cw[4 * fl + 1], cwC = cw[4 * fl + 2], cwD = cw[4 * fl + 3];
        float c0 = resL.x * cwA.x + resL.y * cwA.z + resL.z * cwB.x + resL.w * cwB.z
                 + resH.x * cwC.x + resH.y * cwC.z + resH.z * cwD.x + resH.w * cwD.z;
        float c1 = resL.x * cwA.y + resL.y * cwA.w + resL.z * cwB.y + resL.w * cwB.w
                 + resH.x * cwC.y + resH.y * cwC.w + resH.z * cwD.y + resH.w * cwD.w;
        for (int off = 4; off > 0; off >>= 1) {
            c0 += __shfl_xor(c0, off);
            c1 += __shfl_xor(c1, off);
        }
        if (fl == 0) {
            fout[(size_t)i * 2 + 0] = c0 + cls_b[0];
            fout[(size_t)i * 2 + 1] = c1 + cls_b[1];
        }
    }
}

// ---------------- launch ----------------

extern "C" void kernel_launch(void* const* d_in, const int* in_sizes, int n_in,
                              void* d_out, int out_size, void* d_ws, size_t ws_size,
                              hipStream_t stream) {
    const float* x      = (const float*)d_in[0];
    const int*   ei     = (const int*)d_in[1];
    const float* w0     = (const float*)d_in[2];
    const float* w1     = (const float*)d_in[3];
    const float* w2     = (const float*)d_in[4];
    const float* biases = (const float*)d_in[5];
    const float* gamma  = (const float*)d_in[6];
    const float* beta   = (const float*)d_in[7];
    const float* rmean  = (const float*)d_in[8];
    const float* rvar   = (const float*)d_in[9];
    const float* cls_w  = (const float*)d_in[10];
    const float* cls_b  = (const float*)d_in[11];
    float* out = (float*)d_out;

    const int IN = 128, H = 64;
    const int N = in_sizes[0] / IN;   // 100000
    const int E = in_sizes[1] / 2;    // 1200000

    char* p = (char*)d_ws;
    auto carve = [&](size_t bytes) { void* q = (void*)p; p += (bytes + 255) & ~(size_t)255; return q; };
    float* dinv    = (float*)carve((size_t)N * 4);
    int2*  rowse   = (int2*)carve((size_t)N * 8);
    int*   bucket_fill = (int*)carve((size_t)256 * 4);
    int2*  tmp     = (int2*)carve((size_t)256 * BCAP * 8);
    int*   csr     = (int*)carve((size_t)256 * BCAP * 4);
    __half* tbuf   = (__half*)carve((size_t)N * H * 2);
    __half* hbuf   = (__half*)carve((size_t)N * H * 2);

    int nbuckets = (N + (1 << ABITS) - 1) >> ABITS;   // 196 for N=100000
    int na = (E + ACHUNK - 1) / ACHUNK;               // 293

    hipMemsetAsync(bucket_fill, 0, (size_t)256 * 4, stream);
    bucketA_kernel<<<na, 256, 0, stream>>>(ei, E, bucket_fill, tmp);
    bucketB_kernel<<<nbuckets, 256, 0, stream>>>(tmp, bucket_fill, rowse, dinv, csr, N);

    int gemm_grid = (N + 63) / 64;
    int agg_grid  = (N + 31) / 32;   // 32 nodes per block (4 waves x 8 groups)

    // layer 0
    gemm_kernel<128, float><<<gemm_grid, 256, 0, stream>>>(x, w0, dinv, tbuf, N);
    agg_kernel<false><<<agg_grid, 256, 0, stream>>>(tbuf, dinv, rowse, csr,
        biases + 0, gamma + 0, beta + 0, rmean + 0, rvar + 0, hbuf, nullptr, nullptr, nullptr, N);
    // layer 1
    gemm_kernel<64, __half><<<gemm_grid, 256, 0, stream>>>(hbuf, w1, dinv, tbuf, N);
    agg_kernel<false><<<agg_grid, 256, 0, stream>>>(tbuf, dinv, rowse, csr,
        biases + H, gamma + H, beta + H, rmean + H, rvar + H, hbuf, nullptr, nullptr, nullptr, N);
    // layer 2 + classifier
    gemm_kernel<64, __half><<<gemm_grid, 256, 0, stream>>>(hbuf, w2, dinv, tbuf, N);
    agg_kernel<true><<<agg_grid, 256, 0, stream>>>(tbuf, dinv, rowse, csr,
        biases + 2 * H, gamma + 2 * H, beta + 2 * H, rmean + 2 * H, rvar + 2 * H, nullptr, out, cls_w, cls_b, N);
}

// Round 16
// 258.219 us; speedup vs baseline: 1.1357x; 1.0200x over previous
//
#include <hip/hip_runtime.h>
#include <hip/hip_fp16.h>

#define EPS 1e-5f
#define ABITS 9           // 512 nodes per target-bucket
#define ACHUNK 4096       // edges per block in bucket pass A
#define BCAP 8192         // padded edge capacity per bucket (avg ~6150, >26 sigma margin)
#define CSHIFT 13         // src-chunk = src >> 13 (1 MB of t per chunk)
#define NCHUNK 16
// tmp entry packing: (dstOff << 17) | src  — requires N <= 131072 (N=100000 ok)

typedef _Float16 half8 __attribute__((ext_vector_type(8)));
typedef float floatx4 __attribute__((ext_vector_type(4)));

// ---------------- graph prep (2 kernels, padded buckets, no global scan) ----------------

// A: per-block LDS histogram -> reserve run per bucket via global fill atomics -> scatter.
__global__ __launch_bounds__(256) void bucketA_kernel(const int* __restrict__ ei, int E,
                                                      int* __restrict__ bucket_fill, unsigned* __restrict__ tmp) {
    __shared__ int hist[256], lbase[256], lcur[256];
    int t = threadIdx.x;
    hist[t] = 0; lcur[t] = 0;
    __syncthreads();
    int e0 = blockIdx.x * ACHUNK;
    int e1 = e0 + ACHUNK; if (e1 > E) e1 = E;
    for (int e = e0 + t; e < e1; e += 256)
        atomicAdd(&hist[ei[E + e] >> ABITS], 1);
    __syncthreads();
    int h = hist[t];
    if (h) lbase[t] = atomicAdd(&bucket_fill[t], h);
    __syncthreads();
    for (int e = e0 + t; e < e1; e += 256) {
        int r = ei[e], c = ei[E + e];
        int b = c >> ABITS;
        int l = atomicAdd(&lcur[b], 1);
        tmp[(size_t)b * BCAP + lbase[b] + l] = ((unsigned)(c & 511) << 17) | (unsigned)r;
    }
}

// B: per bucket — stage packed edges in LDS, count (dst,chunk), scan, write
// rowse(int2)+dinv, place src indices grouped by src-chunk within each node's list.
__global__ __launch_bounds__(256) void bucketB_kernel(const unsigned* __restrict__ tmp,
                                                      const int* __restrict__ bucket_fill,
                                                      int2* __restrict__ rowse, float* __restrict__ dinv,
                                                      int* __restrict__ csr, int n) {
    __shared__ unsigned edg[BCAP];          // 32 KB (packed)
    __shared__ int cnt2[512 * NCHUNK];      // 32 KB: counts -> seg cursors
    __shared__ int ps[256];
    int b = blockIdx.x, t = threadIdx.x;
    int n0 = b << ABITS;
    int cntN = n - n0; if (cntN > 512) cntN = 512;
    int ne = bucket_fill[b]; if (ne > BCAP) ne = BCAP;
    int base = b * BCAP;
    for (int i = t; i < 512 * NCHUNK; i += 256) cnt2[i] = 0;
    for (int idx = t; idx < ne; idx += 256) edg[idx] = tmp[(size_t)base + idx];
    __syncthreads();
    for (int idx = t; idx < ne; idx += 256) {
        unsigned e = edg[idx];
        int dstOff = e >> 17, src = e & 0x1FFFF;
        atomicAdd(&cnt2[dstOff * NCHUNK + (src >> CSHIFT)], 1);
    }
    __syncthreads();
    int c0 = 0, c1 = 0;
#pragma unroll
    for (int c = 0; c < NCHUNK; ++c) {
        c0 += cnt2[(2 * t) * NCHUNK + c];
        c1 += cnt2[(2 * t + 1) * NCHUNK + c];
    }
    int s = c0 + c1;
    ps[t] = s;
    __syncthreads();
    for (int off = 1; off < 256; off <<= 1) {
        int u = (t >= off) ? ps[t - off] : 0;
        __syncthreads();
        ps[t] += u;
        __syncthreads();
    }
    int excl = ps[t] - s;
    int st0 = base + excl, st1 = base + excl + c0;
    if (2 * t < cntN) {
        rowse[n0 + 2 * t] = make_int2(st0, st0 + c0);
        dinv[n0 + 2 * t] = rsqrtf((float)(c0 + 1));
    }
    if (2 * t + 1 < cntN) {
        rowse[n0 + 2 * t + 1] = make_int2(st1, st1 + c1);
        dinv[n0 + 2 * t + 1] = rsqrtf((float)(c1 + 1));
    }
    int run = st0;
#pragma unroll
    for (int c = 0; c < NCHUNK; ++c) {
        int v = cnt2[(2 * t) * NCHUNK + c];
        cnt2[(2 * t) * NCHUNK + c] = run;
        run += v;
    }
    run = st1;
#pragma unroll
    for (int c = 0; c < NCHUNK; ++c) {
        int v = cnt2[(2 * t + 1) * NCHUNK + c];
        cnt2[(2 * t + 1) * NCHUNK + c] = run;
        run += v;
    }
    __syncthreads();
    for (int idx = t; idx < ne; idx += 256) {
        unsigned e = edg[idx];
        int dstOff = e >> 17, src = e & 0x1FFFF;
        int key = dstOff * NCHUNK + (src >> CSHIFT);
        int pos = atomicAdd(&cnt2[key], 1);
        csr[pos] = src;
    }
}

// ---------------- dense GEMM via MFMA: [n,K] @ [K,64] -> dinv[row] * result (f16) ----------------

template <int K, typename TIN>
__global__ __launch_bounds__(256) void gemm_kernel(const TIN* __restrict__ A, const float* __restrict__ W,
                                                   const float* __restrict__ dinv, __half* __restrict__ out, int n) {
    const int KP = K + 8;
    __shared__ _Float16 Ah[64 * (K + 8)];
    __shared__ _Float16 Wt[64 * (K + 8)];
    int tid = threadIdx.x;

    for (int idx = tid; idx < K * 64; idx += 256) {
        int k = idx >> 6, c = idx & 63;
        Wt[c * KP + k] = (_Float16)W[idx];
    }
    int row0 = blockIdx.x * 64;
    const TIN* Ab = A + (size_t)row0 * K;
    int limit = (n - row0) * K; if (limit > 64 * K) limit = 64 * K;

    if constexpr (sizeof(TIN) == 4) {   // float input
        for (int f = tid * 4; f < 64 * K; f += 1024) {
            float4 v = make_float4(0.f, 0.f, 0.f, 0.f);
            if (f + 3 < limit) {
                v = *(const float4*)((const float*)Ab + f);
            } else {
                if (f + 0 < limit) v.x = ((const float*)Ab)[f + 0];
                if (f + 1 < limit) v.y = ((const float*)Ab)[f + 1];
                if (f + 2 < limit) v.z = ((const float*)Ab)[f + 2];
            }
            int row = f / K, k = f % K;
            _Float16* dst = Ah + row * KP + k;
            dst[0] = (_Float16)v.x; dst[1] = (_Float16)v.y;
            dst[2] = (_Float16)v.z; dst[3] = (_Float16)v.w;
        }
    } else {                            // fp16 input: straight copy
        for (int f = tid * 8; f < 64 * K; f += 2048) {
            uint4 v = make_uint4(0, 0, 0, 0);
            if (f + 7 < limit) {
                v = *(const uint4*)((const __half*)Ab + f);
            } else {
                const __half* hp = (const __half*)Ab;
                __half tmp8[8];
                for (int j = 0; j < 8; ++j) tmp8[j] = (f + j < limit) ? hp[f + j] : __half(0);
                v = *(const uint4*)tmp8;
            }
            int row = f / K, k = f % K;
            *(uint4*)(Ah + row * KP + k) = v;
        }
    }
    __syncthreads();

    int w = tid >> 6, lane = tid & 63;
    int m = lane & 15, quad = lane >> 4;
    const _Float16* Aw = Ah + (size_t)(w * 16 + m) * KP + quad * 8;
    const _Float16* Bw = Wt + (size_t)m * KP + quad * 8;

    floatx4 acc0 = {0.f, 0.f, 0.f, 0.f}, acc1 = acc0, acc2 = acc0, acc3 = acc0;
    for (int k0 = 0; k0 < K; k0 += 32) {
        half8 a  = *(const half8*)(Aw + k0);
        half8 b0 = *(const half8*)(Bw + 0 * 16 * KP + k0);
        half8 b1 = *(const half8*)(Bw + 1 * 16 * KP + k0);
        half8 b2 = *(const half8*)(Bw + 2 * 16 * KP + k0);
        half8 b3 = *(const half8*)(Bw + 3 * 16 * KP + k0);
        acc0 = __builtin_amdgcn_mfma_f32_16x16x32_f16(a, b0, acc0, 0, 0, 0);
        acc1 = __builtin_amdgcn_mfma_f32_16x16x32_f16(a, b1, acc1, 0, 0, 0);
        acc2 = __builtin_amdgcn_mfma_f32_16x16x32_f16(a, b2, acc2, 0, 0, 0);
        acc3 = __builtin_amdgcn_mfma_f32_16x16x32_f16(a, b3, acc3, 0, 0, 0);
    }

    int rbase = row0 + w * 16 + quad * 4;
#pragma unroll
    for (int r = 0; r < 4; ++r) {
        int row = rbase + r;
        if (row < n) {
            float dv = dinv[row];
            __half* o = out + (size_t)row * 64 + m;
            o[0]  = __float2half(acc0[r] * dv);
            o[16] = __float2half(acc1[r] * dv);
            o[32] = __float2half(acc2[r] * dv);
            o[48] = __float2half(acc3[r] * dv);
        }
    }
}

// ---------------- aggregation + bias + BN(eval) + ReLU (+classifier) ----------------
// Full-row gather (8 lanes x 16 B = one 128 B line/edge). Wave = 8 independent
// 8-lane groups, one node per group. __launch_bounds__(256,4): R15's default
// allocation gave 28 VGPRs — too few to hold 8 in-flight uint4 gathers, so the
// compiler serialized the unroll-8 body. The (256,4) cap (128 VGPR) lets all 8
// stay outstanding; expected VGPR ~64, no spill.

__device__ __forceinline__ void agg_add8(float4& lo, float4& hi, uint4 raw) {
    float2 p0 = __half22float2(*(const __half2*)&raw.x);
    float2 p1 = __half22float2(*(const __half2*)&raw.y);
    float2 p2 = __half22float2(*(const __half2*)&raw.z);
    float2 p3 = __half22float2(*(const __half2*)&raw.w);
    lo.x += p0.x; lo.y += p0.y; lo.z += p1.x; lo.w += p1.y;
    hi.x += p2.x; hi.y += p2.y; hi.z += p3.x; hi.w += p3.y;
}

template <bool FUSE_CLS>
__global__ __launch_bounds__(256, 4) void agg_kernel(const __half* __restrict__ t, const float* __restrict__ dinv,
                                                  const int2* __restrict__ rowse, const int* __restrict__ csr,
                                                  const float* __restrict__ bias, const float* __restrict__ gamma,
                                                  const float* __restrict__ beta, const float* __restrict__ mean,
                                                  const float* __restrict__ var, __half* __restrict__ hout,
                                                  float* __restrict__ fout,
                                                  const float* __restrict__ cls_w, const float* __restrict__ cls_b,
                                                  int n) {
    int wave = threadIdx.x >> 6;
    int lane = threadIdx.x & 63;
    int g = lane >> 3;          // group 0..7 = node slot
    int fl = lane & 7;          // feature octet: features 8fl..8fl+7
    int i = (blockIdx.x * (blockDim.x >> 6) + wave) * 8 + g;
    if (i >= n) return;

    float4 lo = make_float4(0.f, 0.f, 0.f, 0.f);
    float4 hi = make_float4(0.f, 0.f, 0.f, 0.f);

    uint4 self = *(const uint4*)(t + (size_t)i * 64 + fl * 8);
    agg_add8(lo, hi, self);

    int2 se = rowse[i];
    int e = se.x, e1 = se.y;
    for (; e + 8 <= e1; e += 8) {
        int s0 = csr[e + 0], s1 = csr[e + 1], s2 = csr[e + 2], s3 = csr[e + 3];
        int s4 = csr[e + 4], s5 = csr[e + 5], s6 = csr[e + 6], s7 = csr[e + 7];
        uint4 r0 = *(const uint4*)(t + (size_t)s0 * 64 + fl * 8);
        uint4 r1 = *(const uint4*)(t + (size_t)s1 * 64 + fl * 8);
        uint4 r2 = *(const uint4*)(t + (size_t)s2 * 64 + fl * 8);
        uint4 r3 = *(const uint4*)(t + (size_t)s3 * 64 + fl * 8);
        uint4 r4 = *(const uint4*)(t + (size_t)s4 * 64 + fl * 8);
        uint4 r5 = *(const uint4*)(t + (size_t)s5 * 64 + fl * 8);
        uint4 r6 = *(const uint4*)(t + (size_t)s6 * 64 + fl * 8);
        uint4 r7 = *(const uint4*)(t + (size_t)s7 * 64 + fl * 8);
        agg_add8(lo, hi, r0); agg_add8(lo, hi, r1); agg_add8(lo, hi, r2); agg_add8(lo, hi, r3);
        agg_add8(lo, hi, r4); agg_add8(lo, hi, r5); agg_add8(lo, hi, r6); agg_add8(lo, hi, r7);
    }
    if (e + 4 <= e1) {
        int s0 = csr[e + 0], s1 = csr[e + 1], s2 = csr[e + 2], s3 = csr[e + 3];
        uint4 r0 = *(const uint4*)(t + (size_t)s0 * 64 + fl * 8);
        uint4 r1 = *(const uint4*)(t + (size_t)s1 * 64 + fl * 8);
        uint4 r2 = *(const uint4*)(t + (size_t)s2 * 64 + fl * 8);
        uint4 r3 = *(const uint4*)(t + (size_t)s3 * 64 + fl * 8);
        agg_add8(lo, hi, r0); agg_add8(lo, hi, r1); agg_add8(lo, hi, r2); agg_add8(lo, hi, r3);
        e += 4;
    }
    if (e + 2 <= e1) {
        int s0 = csr[e + 0], s1 = csr[e + 1];
        uint4 r0 = *(const uint4*)(t + (size_t)s0 * 64 + fl * 8);
        uint4 r1 = *(const uint4*)(t + (size_t)s1 * 64 + fl * 8);
        agg_add8(lo, hi, r0); agg_add8(lo, hi, r1);
        e += 2;
    }
    if (e < e1) {
        uint4 r0 = *(const uint4*)(t + (size_t)csr[e] * 64 + fl * 8);
        agg_add8(lo, hi, r0);
    }

    float di = dinv[i];
    lo.x *= di; lo.y *= di; lo.z *= di; lo.w *= di;
    hi.x *= di; hi.y *= di; hi.z *= di; hi.w *= di;

    float4 bbL = ((const float4*)bias)[2 * fl],  bbH = ((const float4*)bias)[2 * fl + 1];
    float4 ggL = ((const float4*)gamma)[2 * fl], ggH = ((const float4*)gamma)[2 * fl + 1];
    float4 beL = ((const float4*)beta)[2 * fl],  beH = ((const float4*)beta)[2 * fl + 1];
    float4 mmL = ((const float4*)mean)[2 * fl],  mmH = ((const float4*)mean)[2 * fl + 1];
    float4 vvL = ((const float4*)var)[2 * fl],   vvH = ((const float4*)var)[2 * fl + 1];
    float4 resL, resH;
    resL.x = fmaxf((lo.x + bbL.x - mmL.x) * (ggL.x * rsqrtf(vvL.x + EPS)) + beL.x, 0.f);
    resL.y = fmaxf((lo.y + bbL.y - mmL.y) * (ggL.y * rsqrtf(vvL.y + EPS)) + beL.y, 0.f);
    resL.z = fmaxf((lo.z + bbL.z - mmL.z) * (ggL.z * rsqrtf(vvL.z + EPS)) + beL.z, 0.f);
    resL.w = fmaxf((lo.w + bbL.w - mmL.w) * (ggL.w * rsqrtf(vvL.w + EPS)) + beL.w, 0.f);
    resH.x = fmaxf((hi.x + bbH.x - mmH.x) * (ggH.x * rsqrtf(vvH.x + EPS)) + beH.x, 0.f);
    resH.y = fmaxf((hi.y + bbH.y - mmH.y) * (ggH.y * rsqrtf(vvH.y + EPS)) + beH.y, 0.f);
    resH.z = fmaxf((hi.z + bbH.z - mmH.z) * (ggH.z * rsqrtf(vvH.z + EPS)) + beH.z, 0.f);
    resH.w = fmaxf((hi.w + bbH.w - mmH.w) * (ggH.w * rsqrtf(vvH.w + EPS)) + beH.w, 0.f);

    if (!FUSE_CLS) {
        __half2 h0 = __floats2half2_rn(resL.x, resL.y);
        __half2 h1 = __floats2half2_rn(resL.z, resL.w);
        __half2 h2 = __floats2half2_rn(resH.x, resH.y);
        __half2 h3 = __floats2half2_rn(resH.z, resH.w);
        uint4 pk;
        pk.x = *(unsigned*)&h0; pk.y = *(unsigned*)&h1;
        pk.z = *(unsigned*)&h2; pk.w = *(unsigned*)&h3;
        ((uint4*)hout)[(size_t)i * 8 + fl] = pk;
    } else {
        const float4* cw = (const float4*)cls_w;
        float4 cwA = cw[4 * fl + 0], cwB = cw[4 * fl + 1], cwC = cw[4 * fl + 2], cwD = cw[4 * fl + 3];
        float c0 = resL.x * cwA.x + resL.y * cwA.z + resL.z * cwB.x + resL.w * cwB.z
                 + resH.x * cwC.x + resH.y * cwC.z + resH.z * cwD.x + resH.w * cwD.z;
        float c1 = resL.x * cwA.y + resL.y * cwA.w + resL.z * cwB.y + resL.w * cwB.w
                 + resH.x * cwC.y + resH.y * cwC.w + resH.z * cwD.y + resH.w * cwD.w;
        for (int off = 4; off > 0; off >>= 1) {
            c0 += __shfl_xor(c0, off);
            c1 += __shfl_xor(c1, off);
        }
        if (fl == 0) {
            fout[(size_t)i * 2 + 0] = c0 + cls_b[0];
            fout[(size_t)i * 2 + 1] = c1 + cls_b[1];
        }
    }
}

// ---------------- launch ----------------

extern "C" void kernel_launch(void* const* d_in, const int* in_sizes, int n_in,
                              void* d_out, int out_size, void* d_ws, size_t ws_size,
                              hipStream_t stream) {
    const float* x      = (const float*)d_in[0];
    const int*   ei     = (const int*)d_in[1];
    const float* w0     = (const float*)d_in[2];
    const float* w1     = (const float*)d_in[3];
    const float* w2     = (const float*)d_in[4];
    const float* biases = (const float*)d_in[5];
    const float* gamma  = (const float*)d_in[6];
    const float* beta   = (const float*)d_in[7];
    const float* rmean  = (const float*)d_in[8];
    const float* rvar   = (const float*)d_in[9];
    const float* cls_w  = (const float*)d_in[10];
    const float* cls_b  = (const float*)d_in[11];
    float* out = (float*)d_out;

    const int IN = 128, H = 64;
    const int N = in_sizes[0] / IN;   // 100000
    const int E = in_sizes[1] / 2;    // 1200000

    char* p = (char*)d_ws;
    auto carve = [&](size_t bytes) { void* q = (void*)p; p += (bytes + 255) & ~(size_t)255; return q; };
    float* dinv    = (float*)carve((size_t)N * 4);
    int2*  rowse   = (int2*)carve((size_t)N * 8);
    int*   bucket_fill = (int*)carve((size_t)256 * 4);
    unsigned* tmp  = (unsigned*)carve((size_t)256 * BCAP * 4);
    int*   csr     = (int*)carve((size_t)256 * BCAP * 4);
    __half* tbuf   = (__half*)carve((size_t)N * H * 2);
    __half* hbuf   = (__half*)carve((size_t)N * H * 2);

    int nbuckets = (N + (1 << ABITS) - 1) >> ABITS;   // 196 for N=100000
    int na = (E + ACHUNK - 1) / ACHUNK;               // 293

    hipMemsetAsync(bucket_fill, 0, (size_t)256 * 4, stream);
    bucketA_kernel<<<na, 256, 0, stream>>>(ei, E, bucket_fill, tmp);
    bucketB_kernel<<<nbuckets, 256, 0, stream>>>(tmp, bucket_fill, rowse, dinv, csr, N);

    int gemm_grid = (N + 63) / 64;
    int agg_grid  = (N + 31) / 32;   // 32 nodes per block (4 waves x 8 groups)

    // layer 0
    gemm_kernel<128, float><<<gemm_grid, 256, 0, stream>>>(x, w0, dinv, tbuf, N);
    agg_kernel<false><<<agg_grid, 256, 0, stream>>>(tbuf, dinv, rowse, csr,
        biases + 0, gamma + 0, beta + 0, rmean + 0, rvar + 0, hbuf, nullptr, nullptr, nullptr, N);
    // layer 1
    gemm_kernel<64, __half><<<gemm_grid, 256, 0, stream>>>(hbuf, w1, dinv, tbuf, N);
    agg_kernel<false><<<agg_grid, 256, 0, stream>>>(tbuf, dinv, rowse, csr,
        biases + H, gamma + H, beta + H, rmean + H, rvar + H, hbuf, nullptr, nullptr, nullptr, N);
    // layer 2 + classifier
    gemm_kernel<64, __half><<<gemm_grid, 256, 0, stream>>>(hbuf, w2, dinv, tbuf, N);
    agg_kernel<true><<<agg_grid, 256, 0, stream>>>(tbuf, dinv, rowse, csr,
        biases + 2 * H, gamma + 2 * H, beta + 2 * H, rmean + 2 * H, rvar + 2 * H, nullptr, out, cls_w, cls_b, N);
}

// Round 17
// 251.148 us; speedup vs baseline: 1.1677x; 1.0282x over previous
//
#include <hip/hip_runtime.h>
#include <hip/hip_fp16.h>

#define EPS 1e-5f
#define ABITS 9           // 512 nodes per target-bucket
#define ACHUNK 4096       // edges per block in bucket pass A
#define BCAP 8192         // tmp capacity per bucket (avg ~6150, >26 sigma margin)
#define BCSR 12288        // padded csr capacity per bucket (<= BCAP + 512*7)
#define CSHIFT 13         // src-chunk = src >> 13 (1 MB of t per chunk)
#define NCHUNK 16
// tmp entry packing: (dstOff << 17) | src  — requires N <= 131072 (N=100000 ok)

typedef _Float16 half8 __attribute__((ext_vector_type(8)));
typedef float floatx4 __attribute__((ext_vector_type(4)));

// ---------------- graph prep (2 kernels, padded buckets, no global scan) ----------------

// A: single pass over ei — stage chunk in LDS, LDS histogram, reserve bucket runs,
// scatter packed entries from LDS (ei read once, 9.6 MB total).
__global__ __launch_bounds__(256) void bucketA_kernel(const int* __restrict__ ei, int E,
                                                      int* __restrict__ bucket_fill, unsigned* __restrict__ tmp) {
    __shared__ int2 edg[ACHUNK];            // 32 KB
    __shared__ int hist[256], lbase[256], lcur[256];
    int t = threadIdx.x;
    hist[t] = 0; lcur[t] = 0;
    __syncthreads();
    int e0 = blockIdx.x * ACHUNK;
    int e1 = e0 + ACHUNK; if (e1 > E) e1 = E;
    int ne = e1 - e0;
    for (int idx = t; idx < ne; idx += 256) {
        int r = ei[e0 + idx], c = ei[E + e0 + idx];
        edg[idx] = make_int2(r, c);
        atomicAdd(&hist[c >> ABITS], 1);
    }
    __syncthreads();
    int h = hist[t];
    if (h) lbase[t] = atomicAdd(&bucket_fill[t], h);
    __syncthreads();
    for (int idx = t; idx < ne; idx += 256) {
        int2 e = edg[idx];
        int b = e.y >> ABITS;
        int l = atomicAdd(&lcur[b], 1);
        tmp[(size_t)b * BCAP + lbase[b] + l] = ((unsigned)(e.y & 511) << 17) | (unsigned)e.x;
    }
}

// B: per bucket — stage packed edges in LDS, count (dst,chunk), scan PADDED counts,
// write rowse(start, start+deg) + dinv, place srcs grouped by src-chunk, then pad
// each node's list to a multiple of 8 with src=i (agg corrects with (1-k)*t[i]).
__global__ __launch_bounds__(256) void bucketB_kernel(const unsigned* __restrict__ tmp,
                                                      const int* __restrict__ bucket_fill,
                                                      int2* __restrict__ rowse, float* __restrict__ dinv,
                                                      int* __restrict__ csr, int n) {
    __shared__ unsigned edg[BCAP];          // 32 KB (packed)
    __shared__ int cnt2[512 * NCHUNK];      // 32 KB: counts -> seg cursors
    __shared__ int ps[256];
    int b = blockIdx.x, t = threadIdx.x;
    int n0 = b << ABITS;
    int cntN = n - n0; if (cntN > 512) cntN = 512;
    int ne = bucket_fill[b]; if (ne > BCAP) ne = BCAP;
    int base = b * BCAP;
    int cbase = b * BCSR;
    for (int i = t; i < 512 * NCHUNK; i += 256) cnt2[i] = 0;
    for (int idx = t; idx < ne; idx += 256) edg[idx] = tmp[(size_t)base + idx];
    __syncthreads();
    for (int idx = t; idx < ne; idx += 256) {
        unsigned e = edg[idx];
        int dstOff = e >> 17, src = e & 0x1FFFF;
        atomicAdd(&cnt2[dstOff * NCHUNK + (src >> CSHIFT)], 1);
    }
    __syncthreads();
    int c0 = 0, c1 = 0;
#pragma unroll
    for (int c = 0; c < NCHUNK; ++c) {
        c0 += cnt2[(2 * t) * NCHUNK + c];
        c1 += cnt2[(2 * t + 1) * NCHUNK + c];
    }
    int p0 = (c0 + 7) & ~7, p1 = (c1 + 7) & ~7;   // padded lengths
    int s = p0 + p1;
    ps[t] = s;
    __syncthreads();
    for (int off = 1; off < 256; off <<= 1) {
        int u = (t >= off) ? ps[t - off] : 0;
        __syncthreads();
        ps[t] += u;
        __syncthreads();
    }
    int excl = ps[t] - s;
    int st0 = cbase + excl, st1 = cbase + excl + p0;
    if (2 * t < cntN) {
        rowse[n0 + 2 * t] = make_int2(st0, st0 + c0);
        dinv[n0 + 2 * t] = rsqrtf((float)(c0 + 1));
    }
    if (2 * t + 1 < cntN) {
        rowse[n0 + 2 * t + 1] = make_int2(st1, st1 + c1);
        dinv[n0 + 2 * t + 1] = rsqrtf((float)(c1 + 1));
    }
    // pads: fill [start+deg, start+pdeg) with own node index (self row, L2-hot)
    if (2 * t < cntN)
        for (int j = c0; j < p0; ++j) csr[st0 + j] = n0 + 2 * t;
    if (2 * t + 1 < cntN)
        for (int j = c1; j < p1; ++j) csr[st1 + j] = n0 + 2 * t + 1;
    // counts -> per-(node,chunk) segment cursors
    int run = st0;
#pragma unroll
    for (int c = 0; c < NCHUNK; ++c) {
        int v = cnt2[(2 * t) * NCHUNK + c];
        cnt2[(2 * t) * NCHUNK + c] = run;
        run += v;
    }
    run = st1;
#pragma unroll
    for (int c = 0; c < NCHUNK; ++c) {
        int v = cnt2[(2 * t + 1) * NCHUNK + c];
        cnt2[(2 * t + 1) * NCHUNK + c] = run;
        run += v;
    }
    __syncthreads();
    for (int idx = t; idx < ne; idx += 256) {
        unsigned e = edg[idx];
        int dstOff = e >> 17, src = e & 0x1FFFF;
        int key = dstOff * NCHUNK + (src >> CSHIFT);
        int pos = atomicAdd(&cnt2[key], 1);
        csr[pos] = src;
    }
}

// ---------------- dense GEMM via MFMA: [n,K] @ [K,64] -> dinv[row] * result (f16) ----------------

template <int K, typename TIN>
__global__ __launch_bounds__(256) void gemm_kernel(const TIN* __restrict__ A, const float* __restrict__ W,
                                                   const float* __restrict__ dinv, __half* __restrict__ out, int n) {
    const int KP = K + 8;
    __shared__ _Float16 Ah[64 * (K + 8)];
    __shared__ _Float16 Wt[64 * (K + 8)];
    int tid = threadIdx.x;

    for (int idx = tid; idx < K * 64; idx += 256) {
        int k = idx >> 6, c = idx & 63;
        Wt[c * KP + k] = (_Float16)W[idx];
    }
    int row0 = blockIdx.x * 64;
    const TIN* Ab = A + (size_t)row0 * K;
    int limit = (n - row0) * K; if (limit > 64 * K) limit = 64 * K;

    if constexpr (sizeof(TIN) == 4) {   // float input
        for (int f = tid * 4; f < 64 * K; f += 1024) {
            float4 v = make_float4(0.f, 0.f, 0.f, 0.f);
            if (f + 3 < limit) {
                v = *(const float4*)((const float*)Ab + f);
            } else {
                if (f + 0 < limit) v.x = ((const float*)Ab)[f + 0];
                if (f + 1 < limit) v.y = ((const float*)Ab)[f + 1];
                if (f + 2 < limit) v.z = ((const float*)Ab)[f + 2];
            }
            int row = f / K, k = f % K;
            _Float16* dst = Ah + row * KP + k;
            dst[0] = (_Float16)v.x; dst[1] = (_Float16)v.y;
            dst[2] = (_Float16)v.z; dst[3] = (_Float16)v.w;
        }
    } else {                            // fp16 input: straight copy
        for (int f = tid * 8; f < 64 * K; f += 2048) {
            uint4 v = make_uint4(0, 0, 0, 0);
            if (f + 7 < limit) {
                v = *(const uint4*)((const __half*)Ab + f);
            } else {
                const __half* hp = (const __half*)Ab;
                __half tmp8[8];
                for (int j = 0; j < 8; ++j) tmp8[j] = (f + j < limit) ? hp[f + j] : __half(0);
                v = *(const uint4*)tmp8;
            }
            int row = f / K, k = f % K;
            *(uint4*)(Ah + row * KP + k) = v;
        }
    }
    __syncthreads();

    int w = tid >> 6, lane = tid & 63;
    int m = lane & 15, quad = lane >> 4;
    const _Float16* Aw = Ah + (size_t)(w * 16 + m) * KP + quad * 8;
    const _Float16* Bw = Wt + (size_t)m * KP + quad * 8;

    floatx4 acc0 = {0.f, 0.f, 0.f, 0.f}, acc1 = acc0, acc2 = acc0, acc3 = acc0;
    for (int k0 = 0; k0 < K; k0 += 32) {
        half8 a  = *(const half8*)(Aw + k0);
        half8 b0 = *(const half8*)(Bw + 0 * 16 * KP + k0);
        half8 b1 = *(const half8*)(Bw + 1 * 16 * KP + k0);
        half8 b2 = *(const half8*)(Bw + 2 * 16 * KP + k0);
        half8 b3 = *(const half8*)(Bw + 3 * 16 * KP + k0);
        acc0 = __builtin_amdgcn_mfma_f32_16x16x32_f16(a, b0, acc0, 0, 0, 0);
        acc1 = __builtin_amdgcn_mfma_f32_16x16x32_f16(a, b1, acc1, 0, 0, 0);
        acc2 = __builtin_amdgcn_mfma_f32_16x16x32_f16(a, b2, acc2, 0, 0, 0);
        acc3 = __builtin_amdgcn_mfma_f32_16x16x32_f16(a, b3, acc3, 0, 0, 0);
    }

    int rbase = row0 + w * 16 + quad * 4;
#pragma unroll
    for (int r = 0; r < 4; ++r) {
        int row = rbase + r;
        if (row < n) {
            float dv = dinv[row];
            __half* o = out + (size_t)row * 64 + m;
            o[0]  = __float2half(acc0[r] * dv);
            o[16] = __float2half(acc1[r] * dv);
            o[32] = __float2half(acc2[r] * dv);
            o[48] = __float2half(acc3[r] * dv);
        }
    }
}

// ---------------- aggregation + bias + BN(eval) + ReLU (+classifier) ----------------
// Full-row gather (8 lanes x 16 B = one 128 B line/edge). Wave = 8 independent
// 8-lane groups, one node per group. Lists padded to x8 with src=i (hot line),
// corrected by (1-k)*t[i] -> single uniform unroll-8 loop, no tail tiers.
// __launch_bounds__(256,4): keep >=8 uint4 gathers in registers.

__device__ __forceinline__ void agg_add8(float4& lo, float4& hi, uint4 raw) {
    float2 p0 = __half22float2(*(const __half2*)&raw.x);
    float2 p1 = __half22float2(*(const __half2*)&raw.y);
    float2 p2 = __half22float2(*(const __half2*)&raw.z);
    float2 p3 = __half22float2(*(const __half2*)&raw.w);
    lo.x += p0.x; lo.y += p0.y; lo.z += p1.x; lo.w += p1.y;
    hi.x += p2.x; hi.y += p2.y; hi.z += p3.x; hi.w += p3.y;
}

template <bool FUSE_CLS>
__global__ __launch_bounds__(256, 4) void agg_kernel(const __half* __restrict__ t, const float* __restrict__ dinv,
                                                  const int2* __restrict__ rowse, const int* __restrict__ csr,
                                                  const float* __restrict__ bias, const float* __restrict__ gamma,
                                                  const float* __restrict__ beta, const float* __restrict__ mean,
                                                  const float* __restrict__ var, __half* __restrict__ hout,
                                                  float* __restrict__ fout,
                                                  const float* __restrict__ cls_w, const float* __restrict__ cls_b,
                                                  int n) {
    int wave = threadIdx.x >> 6;
    int lane = threadIdx.x & 63;
    int g = lane >> 3;          // group 0..7 = node slot
    int fl = lane & 7;          // feature octet: features 8fl..8fl+7
    int i = (blockIdx.x * (blockDim.x >> 6) + wave) * 8 + g;
    if (i >= n) return;

    // self row (prefetch; also the pad-correction operand)
    uint4 self = *(const uint4*)(t + (size_t)i * 64 + fl * 8);

    float4 lo = make_float4(0.f, 0.f, 0.f, 0.f);
    float4 hi = make_float4(0.f, 0.f, 0.f, 0.f);

    int2 se = rowse[i];
    int deg = se.y - se.x;
    int padEnd = se.x + ((deg + 7) & ~7);
    for (int e = se.x; e < padEnd; e += 8) {
        int s0 = csr[e + 0], s1 = csr[e + 1], s2 = csr[e + 2], s3 = csr[e + 3];
        int s4 = csr[e + 4], s5 = csr[e + 5], s6 = csr[e + 6], s7 = csr[e + 7];
        uint4 r0 = *(const uint4*)(t + (size_t)s0 * 64 + fl * 8);
        uint4 r1 = *(const uint4*)(t + (size_t)s1 * 64 + fl * 8);
        uint4 r2 = *(const uint4*)(t + (size_t)s2 * 64 + fl * 8);
        uint4 r3 = *(const uint4*)(t + (size_t)s3 * 64 + fl * 8);
        uint4 r4 = *(const uint4*)(t + (size_t)s4 * 64 + fl * 8);
        uint4 r5 = *(const uint4*)(t + (size_t)s5 * 64 + fl * 8);
        uint4 r6 = *(const uint4*)(t + (size_t)s6 * 64 + fl * 8);
        uint4 r7 = *(const uint4*)(t + (size_t)s7 * 64 + fl * 8);
        agg_add8(lo, hi, r0); agg_add8(lo, hi, r1); agg_add8(lo, hi, r2); agg_add8(lo, hi, r3);
        agg_add8(lo, hi, r4); agg_add8(lo, hi, r5); agg_add8(lo, hi, r6); agg_add8(lo, hi, r7);
    }

    // pad correction: padSum included k copies of t[i]; want edges + 1*t[i]
    float coef = 1.0f - (float)(padEnd - se.y);
    {
        float2 p0 = __half22float2(*(const __half2*)&self.x);
        float2 p1 = __half22float2(*(const __half2*)&self.y);
        float2 p2 = __half22float2(*(const __half2*)&self.z);
        float2 p3 = __half22float2(*(const __half2*)&self.w);
        lo.x += coef * p0.x; lo.y += coef * p0.y; lo.z += coef * p1.x; lo.w += coef * p1.y;
        hi.x += coef * p2.x; hi.y += coef * p2.y; hi.z += coef * p3.x; hi.w += coef * p3.y;
    }

    float di = dinv[i];
    lo.x *= di; lo.y *= di; lo.z *= di; lo.w *= di;
    hi.x *= di; hi.y *= di; hi.z *= di; hi.w *= di;

    float4 bbL = ((const float4*)bias)[2 * fl],  bbH = ((const float4*)bias)[2 * fl + 1];
    float4 ggL = ((const float4*)gamma)[2 * fl], ggH = ((const float4*)gamma)[2 * fl + 1];
    float4 beL = ((const float4*)beta)[2 * fl],  beH = ((const float4*)beta)[2 * fl + 1];
    float4 mmL = ((const float4*)mean)[2 * fl],  mmH = ((const float4*)mean)[2 * fl + 1];
    float4 vvL = ((const float4*)var)[2 * fl],   vvH = ((const float4*)var)[2 * fl + 1];
    float4 resL, resH;
    resL.x = fmaxf((lo.x + bbL.x - mmL.x) * (ggL.x * rsqrtf(vvL.x + EPS)) + beL.x, 0.f);
    resL.y = fmaxf((lo.y + bbL.y - mmL.y) * (ggL.y * rsqrtf(vvL.y + EPS)) + beL.y, 0.f);
    resL.z = fmaxf((lo.z + bbL.z - mmL.z) * (ggL.z * rsqrtf(vvL.z + EPS)) + beL.z, 0.f);
    resL.w = fmaxf((lo.w + bbL.w - mmL.w) * (ggL.w * rsqrtf(vvL.w + EPS)) + beL.w, 0.f);
    resH.x = fmaxf((hi.x + bbH.x - mmH.x) * (ggH.x * rsqrtf(vvH.x + EPS)) + beH.x, 0.f);
    resH.y = fmaxf((hi.y + bbH.y - mmH.y) * (ggH.y * rsqrtf(vvH.y + EPS)) + beH.y, 0.f);
    resH.z = fmaxf((hi.z + bbH.z - mmH.z) * (ggH.z * rsqrtf(vvH.z + EPS)) + beH.z, 0.f);
    resH.w = fmaxf((hi.w + bbH.w - mmH.w) * (ggH.w * rsqrtf(vvH.w + EPS)) + beH.w, 0.f);

    if (!FUSE_CLS) {
        __half2 h0 = __floats2half2_rn(resL.x, resL.y);
        __half2 h1 = __floats2half2_rn(resL.z, resL.w);
        __half2 h2 = __floats2half2_rn(resH.x, resH.y);
        __half2 h3 = __floats2half2_rn(resH.z, resH.w);
        uint4 pk;
        pk.x = *(unsigned*)&h0; pk.y = *(unsigned*)&h1;
        pk.z = *(unsigned*)&h2; pk.w = *(unsigned*)&h3;
        ((uint4*)hout)[(size_t)i * 8 + fl] = pk;
    } else {
        const float4* cw = (const float4*)cls_w;
        float4 cwA = cw[4 * fl + 0], cwB = cw[4 * fl + 1], cwC = cw[4 * fl + 2], cwD = cw[4 * fl + 3];
        float c0 = resL.x * cwA.x + resL.y * cwA.z + resL.z * cwB.x + resL.w * cwB.z
                 + resH.x * cwC.x + resH.y * cwC.z + resH.z * cwD.x + resH.w * cwD.z;
        float c1 = resL.x * cwA.y + resL.y * cwA.w + resL.z * cwB.y + resL.w * cwB.w
                 + resH.x * cwC.y + resH.y * cwC.w + resH.z * cwD.y + resH.w * cwD.w;
        for (int off = 4; off > 0; off >>= 1) {
            c0 += __shfl_xor(c0, off);
            c1 += __shfl_xor(c1, off);
        }
        if (fl == 0) {
            fout[(size_t)i * 2 + 0] = c0 + cls_b[0];
            fout[(size_t)i * 2 + 1] = c1 + cls_b[1];
        }
    }
}

// ---------------- launch ----------------

extern "C" void kernel_launch(void* const* d_in, const int* in_sizes, int n_in,
                              void* d_out, int out_size, void* d_ws, size_t ws_size,
                              hipStream_t stream) {
    const float* x      = (const float*)d_in[0];
    const int*   ei     = (const int*)d_in[1];
    const float* w0     = (const float*)d_in[2];
    const float* w1     = (const float*)d_in[3];
    const float* w2     = (const float*)d_in[4];
    const float* biases = (const float*)d_in[5];
    const float* gamma  = (const float*)d_in[6];
    const float* beta   = (const float*)d_in[7];
    const float* rmean  = (const float*)d_in[8];
    const float* rvar   = (const float*)d_in[9];
    const float* cls_w  = (const float*)d_in[10];
    const float* cls_b  = (const float*)d_in[11];
    float* out = (float*)d_out;

    const int IN = 128, H = 64;
    const int N = in_sizes[0] / IN;   // 100000
    const int E = in_sizes[1] / 2;    // 1200000

    char* p = (char*)d_ws;
    auto carve = [&](size_t bytes) { void* q = (void*)p; p += (bytes + 255) & ~(size_t)255; return q; };
    float* dinv    = (float*)carve((size_t)N * 4);
    int2*  rowse   = (int2*)carve((size_t)N * 8);
    int*   bucket_fill = (int*)carve((size_t)256 * 4);
    unsigned* tmp  = (unsigned*)carve((size_t)256 * BCAP * 4);
    int*   csr     = (int*)carve((size_t)256 * BCSR * 4);
    __half* tbuf   = (__half*)carve((size_t)N * H * 2);
    __half* hbuf   = (__half*)carve((size_t)N * H * 2);

    int nbuckets = (N + (1 << ABITS) - 1) >> ABITS;   // 196 for N=100000
    int na = (E + ACHUNK - 1) / ACHUNK;               // 293

    hipMemsetAsync(bucket_fill, 0, (size_t)256 * 4, stream);
    bucketA_kernel<<<na, 256, 0, stream>>>(ei, E, bucket_fill, tmp);
    bucketB_kernel<<<nbuckets, 256, 0, stream>>>(tmp, bucket_fill, rowse, dinv, csr, N);

    int gemm_grid = (N + 63) / 64;
    int agg_grid  = (N + 31) / 32;   // 32 nodes per block (4 waves x 8 groups)

    // layer 0
    gemm_kernel<128, float><<<gemm_grid, 256, 0, stream>>>(x, w0, dinv, tbuf, N);
    agg_kernel<false><<<agg_grid, 256, 0, stream>>>(tbuf, dinv, rowse, csr,
        biases + 0, gamma + 0, beta + 0, rmean + 0, rvar + 0, hbuf, nullptr, nullptr, nullptr, N);
    // layer 1
    gemm_kernel<64, __half><<<gemm_grid, 256, 0, stream>>>(hbuf, w1, dinv, tbuf, N);
    agg_kernel<false><<<agg_grid, 256, 0, stream>>>(tbuf, dinv, rowse, csr,
        biases + H, gamma + H, beta + H, rmean + H, rvar + H, hbuf, nullptr, nullptr, nullptr, N);
    // layer 2 + classifier
    gemm_kernel<64, __half><<<gemm_grid, 256, 0, stream>>>(hbuf, w2, dinv, tbuf, N);
    agg_kernel<true><<<agg_grid, 256, 0, stream>>>(tbuf, dinv, rowse, csr,
        biases + 2 * H, gamma + 2 * H, beta + 2 * H, rmean + 2 * H, rvar + 2 * H, nullptr, out, cls_w, cls_b, N);
}